// Round 1
// baseline (237.641 us; speedup 1.0000x reference)
//
#include <hip/hip_runtime.h>
#include <math.h>

#define Q 100
#define NC 81
#define NV 117
#define VS_STRIDE 101   // pad 100 -> 101 to spread LDS banks on strided reads

// One block per batch element. 256 threads.
// LDS budget: vs_t 117*101*4 = 47268 B + 3*1600 (masks) + 4*400 = 53668 B -> 3 blocks/CU.
__global__ __launch_bounds__(256) void hoi_kernel(
    const float* __restrict__ obj_logits,   // (B,Q,81)
    const float* __restrict__ verb_logits,  // (B,Q,117)
    const float* __restrict__ sub_boxes,    // (B,Q,4) cxcywh
    const float* __restrict__ obj_boxes,    // (B,Q,4)
    const int*   __restrict__ target_sizes, // (B,2) h,w
    float* __restrict__ out_vs,             // (B,Q,117)
    float* __restrict__ out_scores,         // (B,Q)
    float* __restrict__ out_labels,         // (B,2Q) as float
    float* __restrict__ out_boxes)          // (B,2Q,4)
{
    __shared__ __align__(16) float vs_t[NV * VS_STRIDE];  // vs transposed: [v][q]
    __shared__ unsigned long long mask_s[2 * Q];    // conflict mask, 100 bits per query
    __shared__ unsigned long long killed_s[2 * Q];  // per query: bitset of steps it was killed at
    __shared__ unsigned long long killset_s[2 * Q]; // per step i: bitset of queries killed at step i
    __shared__ float score_s[Q];
    __shared__ int   label_s[Q];
    __shared__ int   clist_s[Q];
    __shared__ float col_s[Q];

    const int b   = blockIdx.x;
    const int tid = threadIdx.x;

    // Alias scratch for boxes into vs_t (overwritten later in phase B2).
    float4* sb4    = reinterpret_cast<float4*>(vs_t);   // [0..100) float4
    float4* ob4    = sb4 + Q;                           // [100..200) float4
    float*  area_s = vs_t + 800;
    float*  area_o = vs_t + 900;

    // ---------------- Phase A: softmax/argmax (t<100) and boxes (100<=t<200) ----
    if (tid < Q) {
        const int q = tid;
        const float* lp = obj_logits + (size_t)(b * Q + q) * NC;
        float m = lp[0];
        #pragma unroll 4
        for (int c = 1; c < NC; ++c) m = fmaxf(m, lp[c]);
        float s = 0.f;
        #pragma unroll 4
        for (int c = 0; c < NC; ++c) s += expf(lp[c] - m);
        // argmax over first 80 classes (softmax monotone -> argmax of logits, first-max wins)
        float bl = lp[0]; int bi = 0;
        for (int c = 1; c < NC - 1; ++c) { float lc = lp[c]; if (lc > bl) { bl = lc; bi = c; } }
        float sc = __fdiv_rn(expf(bl - m), s);
        score_s[q] = sc;
        label_s[q] = bi;
        out_scores[(size_t)b * Q + q] = sc;
        out_labels[(size_t)b * 2 * Q + q] = 0.0f;          // SUBJECT_CATEGORY_ID
        out_labels[(size_t)b * 2 * Q + Q + q] = (float)bi;
    } else if (tid < 2 * Q) {
        const int q = tid - Q;
        const float fh = (float)target_sizes[2 * b];
        const float fw = (float)target_sizes[2 * b + 1];
        // NOTE: __f*_rn intrinsics block FMA contraction -> bit-identical to numpy ref.
        float4 sbb = reinterpret_cast<const float4*>(sub_boxes)[(size_t)b * Q + q];
        float hw = __fmul_rn(0.5f, sbb.z);
        float hh = __fmul_rn(0.5f, sbb.w);
        float4 sbox;
        sbox.x = __fmul_rn(__fsub_rn(sbb.x, hw), fw);
        sbox.y = __fmul_rn(__fsub_rn(sbb.y, hh), fh);
        sbox.z = __fmul_rn(__fadd_rn(sbb.x, hw), fw);
        sbox.w = __fmul_rn(__fadd_rn(sbb.y, hh), fh);
        sb4[q] = sbox;
        area_s[q] = __fmul_rn(__fsub_rn(sbox.z, sbox.x), __fsub_rn(sbox.w, sbox.y));
        reinterpret_cast<float4*>(out_boxes)[(size_t)b * 2 * Q + q] = sbox;

        float4 obb = reinterpret_cast<const float4*>(obj_boxes)[(size_t)b * Q + q];
        hw = __fmul_rn(0.5f, obb.z);
        hh = __fmul_rn(0.5f, obb.w);
        float4 obox;
        obox.x = __fmul_rn(__fsub_rn(obb.x, hw), fw);
        obox.y = __fmul_rn(__fsub_rn(obb.y, hh), fh);
        obox.z = __fmul_rn(__fadd_rn(obb.x, hw), fw);
        obox.w = __fmul_rn(__fadd_rn(obb.y, hh), fh);
        ob4[q] = obox;
        area_o[q] = __fmul_rn(__fsub_rn(obox.z, obox.x), __fsub_rn(obox.w, obox.y));
        reinterpret_cast<float4*>(out_boxes)[(size_t)b * 2 * Q + Q + q] = obox;
    }
    __syncthreads();

    // ---------------- Phase B1: conflict masks (t<200: (j, word)) -------------
    if (tid < 2 * Q) {
        const int j = tid >> 1;
        const int wsel = tid & 1;
        const int k0 = wsel * 64;
        const int k1 = wsel ? Q : 64;
        const float4 sj = sb4[j]; const float asj = area_s[j];
        const float4 oj = ob4[j]; const float aoj = area_o[j];
        const int lj = label_s[j];
        unsigned long long bits = 0ull;
        for (int k = k0; k < k1; ++k) {
            if (k == j || label_s[k] != lj) continue;
            float4 sk = sb4[k];
            float wx = fmaxf(__fsub_rn(fminf(sj.z, sk.z), fmaxf(sj.x, sk.x)), 0.f);
            float wy = fmaxf(__fsub_rn(fminf(sj.w, sk.w), fmaxf(sj.y, sk.y)), 0.f);
            float inter = __fmul_rn(wx, wy);
            float uni = __fsub_rn(__fadd_rn(asj, area_s[k]), inter);
            float ious = __fdiv_rn(inter, uni);
            float4 ok = ob4[k];
            wx = fmaxf(__fsub_rn(fminf(oj.z, ok.z), fmaxf(oj.x, ok.x)), 0.f);
            wy = fmaxf(__fsub_rn(fminf(oj.w, ok.w), fmaxf(oj.y, ok.y)), 0.f);
            inter = __fmul_rn(wx, wy);
            uni = __fsub_rn(__fadd_rn(aoj, area_o[k]), inter);
            float iouo = __fdiv_rn(inter, uni);
            if (ious != ious || iouo != iouo) continue;   // np.minimum NaN semantics -> compare false
            if (fminf(ious, iouo) > 0.7f) bits |= 1ull << (k - k0);
        }
        mask_s[2 * j + wsel] = bits;
        killed_s[tid] = 0ull;
        killset_s[tid] = 0ull;
    }
    __syncthreads();   // masks done; alias region (sb/ob/areas) now dead

    // ---------------- Phase B2: vs = sigmoid(verb)*obj_score, transposed ------
    for (int idx = tid; idx < Q * NV; idx += 256) {
        int q = idx / NV;
        int v = idx - q * NV;
        float x = verb_logits[(size_t)b * Q * NV + idx];
        float sg = __fdiv_rn(1.0f, __fadd_rn(1.0f, expf(-x)));
        vs_t[v * VS_STRIDE + q] = __fmul_rn(sg, score_s[q]);
    }
    __syncthreads();

    // ---------------- Phase C/D: sequential PNMS over contested queries -------
    // Key reductions vs reference:
    //  * steps i>=100 are JAX OOB-scatter no-ops
    //  * mask is symmetric & static -> queries with empty mask never interact;
    //    greedy outcome depends only on the contested subset's relative order.
    if (tid == 0) {
        int K = 0;
        for (int q = 0; q < Q; ++q)
            if (mask_s[2 * q] | mask_s[2 * q + 1]) clist_s[K++] = q;
        if (K > 0) {
            for (int i = 0; i < Q; ++i) {
                // gather current column-i scores of contested queries
                for (int k = 0; k < K; ++k) {
                    int c = clist_s[k];
                    float v = vs_t[i * VS_STRIDE + c];
                    if ((killed_s[2 * c + (i >> 6)] >> (i & 63)) & 1ull)
                        v = __fsub_rn(v, 1.0f);
                    col_s[k] = v;
                }
                unsigned long long alive0 = ~0ull, alive1 = (1ull << 36) - 1;
                unsigned long long supp0 = 0ull, supp1 = 0ull;
                // selection (desc, ties -> lower index = stable argsort(-col))
                for (int t = 0; t < K; ++t) {
                    float best = col_s[0]; int bk = 0;
                    for (int k = 1; k < K; ++k) { float ck = col_s[k]; if (ck > best) { best = ck; bk = k; } }
                    col_s[bk] = -3.0e38f;
                    int q = clist_s[bk];
                    bool al = (q < 64) ? ((alive0 >> q) & 1ull) : ((alive1 >> (q - 64)) & 1ull);
                    if (al) {
                        unsigned long long m0 = mask_s[2 * q], m1 = mask_s[2 * q + 1];
                        supp0 |= alive0 & m0;
                        supp1 |= alive1 & m1;
                        alive0 &= ~m0;
                        alive1 &= ~m1;
                        if (q < 64) alive0 &= ~(1ull << q); else alive1 &= ~(1ull << (q - 64));
                    }
                }
                killset_s[2 * i] = supp0;
                killset_s[2 * i + 1] = supp1;
                if (supp0 | supp1) {
                    unsigned long long bi = 1ull << (i & 63);
                    int wsel = i >> 6;
                    for (int k = 0; k < K; ++k) {
                        int c = clist_s[k];
                        unsigned long long sbit = (c < 64) ? (supp0 >> c) : (supp1 >> (c - 64));
                        if (sbit & 1ull) killed_s[2 * c + wsel] |= bi;
                    }
                }
            }
        }
    }
    __syncthreads();

    // ---------------- Phase E: write vs with suppression deltas ---------------
    for (int idx = tid; idx < Q * NV; idx += 256) {
        int q = idx / NV;
        int v = idx - q * NV;
        float val = vs_t[v * VS_STRIDE + q];
        if (v < Q) {
            if ((killset_s[2 * q + (v >> 6)] >> (v & 63)) & 1ull)
                val = __fsub_rn(val, 1.0f);
        }
        out_vs[(size_t)b * Q * NV + idx] = val;
    }
}

extern "C" void kernel_launch(void* const* d_in, const int* in_sizes, int n_in,
                              void* d_out, int out_size, void* d_ws, size_t ws_size,
                              hipStream_t stream) {
    const float* obj_logits   = (const float*)d_in[0];
    const float* verb_logits  = (const float*)d_in[1];
    const float* sub_boxes    = (const float*)d_in[2];
    const float* obj_boxes    = (const float*)d_in[3];
    const int*   target_sizes = (const int*)d_in[4];
    const int B = in_sizes[0] / (Q * NC);   // 1024

    float* out_vs     = (float*)d_out;                       // B*Q*117
    float* out_scores = out_vs + (size_t)B * Q * NV;          // B*Q
    float* out_labels = out_scores + (size_t)B * Q;           // B*2Q
    float* out_boxes  = out_labels + (size_t)B * 2 * Q;       // B*2Q*4

    hoi_kernel<<<dim3(B), dim3(256), 0, stream>>>(
        obj_logits, verb_logits, sub_boxes, obj_boxes, target_sizes,
        out_vs, out_scores, out_labels, out_boxes);
}

// Round 2
// 180.507 us; speedup vs baseline: 1.3165x; 1.3165x over previous
//
#include <hip/hip_runtime.h>
#include <math.h>

#define Q 100
#define NC 81
#define NV 117

// ---------------------------------------------------------------------------
// K1: softmax score + argmax label. ONE WAVE PER QUERY (64 lanes cover 81
// logits: lane and lane+64). Fully coalesced 256B loads, shuffle reductions,
// zero LDS -> full occupancy.
// ---------------------------------------------------------------------------
__global__ __launch_bounds__(256) void k_scores(
    const float* __restrict__ obj_logits,   // (B*Q, 81)
    float* __restrict__ out_scores,         // (B*Q)
    float* __restrict__ out_labels,         // (B, 2Q) as float
    int BQ)
{
    const int w    = blockIdx.x * 4 + (threadIdx.x >> 6);
    const int lane = threadIdx.x & 63;
    if (w >= BQ) return;
    const float* lp = obj_logits + (size_t)w * NC;

    float l0 = lp[lane];
    float l1 = (lane < NC - 64) ? lp[64 + lane] : -INFINITY;

    // max over all 81 (softmax stabilizer)
    float m = fmaxf(l0, l1);
    #pragma unroll
    for (int d = 1; d < 64; d <<= 1) m = fmaxf(m, __shfl_xor(m, d));

    // sum of exp
    float s = expf(l0 - m) + ((lane < NC - 64) ? expf(l1 - m) : 0.f);
    #pragma unroll
    for (int d = 1; d < 64; d <<= 1) s += __shfl_xor(s, d);

    // argmax over first 80 classes, first-max-wins (softmax is monotone)
    float bv = l0; int bi = lane;
    if (lane < 16 && l1 > bv) { bv = l1; bi = 64 + lane; }  // idx 64+lane <= 79
    #pragma unroll
    for (int d = 1; d < 64; d <<= 1) {
        float ov = __shfl_xor(bv, d);
        int   oi = __shfl_xor(bi, d);
        if (ov > bv || (ov == bv && oi < bi)) { bv = ov; bi = oi; }
    }

    if (lane == 0) {
        float sc = __fdiv_rn(expf(bv - m), s);
        int b = w / Q, qq = w - b * Q;
        out_scores[w] = sc;
        out_labels[(size_t)b * 2 * Q + qq]     = 0.0f;       // SUBJECT_CATEGORY_ID
        out_labels[(size_t)b * 2 * Q + Q + qq] = (float)bi;
    }
}

// ---------------------------------------------------------------------------
// K2: vs = sigmoid(verb_logits) * obj_score. Flat float4 streaming
// (B*Q*117 is divisible by 4). scores[] is 400 KB -> L2-resident broadcast.
// ---------------------------------------------------------------------------
__global__ __launch_bounds__(256) void k_vs(
    const float4* __restrict__ verb4,
    const float*  __restrict__ scores,
    float4* __restrict__ out4,
    int n4)
{
    const int i = blockIdx.x * 256 + threadIdx.x;
    if (i >= n4) return;
    float4 x = verb4[i];
    const int e = i * 4;
    float xv[4] = {x.x, x.y, x.z, x.w};
    float r[4];
    #pragma unroll
    for (int j = 0; j < 4; ++j) {
        int q = (e + j) / NV;                 // compiler magic-mul
        float sg = __fdiv_rn(1.0f, __fadd_rn(1.0f, expf(-xv[j])));
        r[j] = __fmul_rn(sg, scores[q]);
    }
    out4[i] = make_float4(r[0], r[1], r[2], r[3]);
}

// ---------------------------------------------------------------------------
// K3: boxes (xyxy*scale) + pair-NMS fixup. One block per batch.
// Fast path: no conflicting pair -> write boxes and exit (common case).
// Slow path: stage contested vs rows to LDS, thread-0 serial greedy
// (reference semantics incl. the row-i scatter quirk and OOB-drop for
// class-steps >= 100), parallel RMW of the few suppressed entries.
// ---------------------------------------------------------------------------
__global__ __launch_bounds__(256) void k_pnms(
    const float* __restrict__ sub_boxes,    // (B,Q,4) cxcywh
    const float* __restrict__ obj_boxes,    // (B,Q,4)
    const int*   __restrict__ target_sizes, // (B,2) h,w
    const float* __restrict__ out_labels,   // (B,2Q) float (obj labels at +Q)
    float* __restrict__ out_vs,             // (B,Q,117) already written by K2
    float* __restrict__ out_boxes)          // (B,2Q,4)
{
    __shared__ float4 sb4[Q], ob4[Q];
    __shared__ float  area_s[Q], area_o[Q], label_s[Q];
    __shared__ unsigned long long mask_s[2 * Q];    // conflict mask per query
    __shared__ unsigned long long killset_s[2 * Q]; // per step i: queries killed at i
    __shared__ int   clist_s[Q];
    __shared__ float col_s[Q];
    __shared__ float vsrow[Q * 101];  // staged vs rows of contested queries
    __shared__ int   anyconf, Ksh;

    const int b   = blockIdx.x;
    const int tid = threadIdx.x;

    if (tid == 0) anyconf = 0;
    if (tid < 2 * Q) killset_s[tid] = 0ull;

    // ---- boxes (bit-exact: __f*_rn blocks FMA contraction, matches np) ----
    if (tid < 2 * Q) {
        const int q = (tid < Q) ? tid : tid - Q;
        const float fh = (float)target_sizes[2 * b];
        const float fw = (float)target_sizes[2 * b + 1];
        const float4* src = reinterpret_cast<const float4*>(tid < Q ? sub_boxes : obj_boxes);
        float4 cxy = src[(size_t)b * Q + q];
        float hw = __fmul_rn(0.5f, cxy.z);
        float hh = __fmul_rn(0.5f, cxy.w);
        float4 box;
        box.x = __fmul_rn(__fsub_rn(cxy.x, hw), fw);
        box.y = __fmul_rn(__fsub_rn(cxy.y, hh), fh);
        box.z = __fmul_rn(__fadd_rn(cxy.x, hw), fw);
        box.w = __fmul_rn(__fadd_rn(cxy.y, hh), fh);
        float area = __fmul_rn(__fsub_rn(box.z, box.x), __fsub_rn(box.w, box.y));
        if (tid < Q) {
            sb4[q] = box; area_s[q] = area;
            reinterpret_cast<float4*>(out_boxes)[(size_t)b * 2 * Q + q] = box;
            label_s[q] = out_labels[(size_t)b * 2 * Q + Q + q];
        } else {
            ob4[q] = box; area_o[q] = area;
            reinterpret_cast<float4*>(out_boxes)[(size_t)b * 2 * Q + Q + q] = box;
        }
    }
    __syncthreads();

    // ---- conflict masks: thread (j, word) covers 64 or 36 candidates ----
    if (tid < 2 * Q) {
        const int j = tid >> 1;
        const int wsel = tid & 1;
        const int k0 = wsel * 64;
        const int k1 = wsel ? Q : 64;
        const float4 sj = sb4[j]; const float asj = area_s[j];
        const float4 oj = ob4[j]; const float aoj = area_o[j];
        const float  lj = label_s[j];
        unsigned long long bits = 0ull;
        for (int k = k0; k < k1; ++k) {
            if (k == j || label_s[k] != lj) continue;
            float4 sk = sb4[k];
            float wx = fmaxf(__fsub_rn(fminf(sj.z, sk.z), fmaxf(sj.x, sk.x)), 0.f);
            float wy = fmaxf(__fsub_rn(fminf(sj.w, sk.w), fmaxf(sj.y, sk.y)), 0.f);
            float inter = __fmul_rn(wx, wy);
            float uni = __fsub_rn(__fadd_rn(asj, area_s[k]), inter);
            float ious = __fdiv_rn(inter, uni);
            float4 ok = ob4[k];
            wx = fmaxf(__fsub_rn(fminf(oj.z, ok.z), fmaxf(oj.x, ok.x)), 0.f);
            wy = fmaxf(__fsub_rn(fminf(oj.w, ok.w), fmaxf(oj.y, ok.y)), 0.f);
            inter = __fmul_rn(wx, wy);
            uni = __fsub_rn(__fadd_rn(aoj, area_o[k]), inter);
            float iouo = __fdiv_rn(inter, uni);
            if (ious != ious || iouo != iouo) continue;  // np.minimum NaN -> compare false
            if (fminf(ious, iouo) > 0.7f) bits |= 1ull << (k - k0);
        }
        mask_s[tid] = bits;          // mask_s[2*j+wsel]
        if (bits) anyconf = 1;       // benign race, same value
    }
    __syncthreads();

    if (!anyconf) return;            // fast path: boxes written, vs untouched

    // ---- contested list ----
    if (tid == 0) {
        int K = 0;
        for (int q = 0; q < Q; ++q)
            if (mask_s[2 * q] | mask_s[2 * q + 1]) clist_s[K++] = q;
        Ksh = K;
    }
    __syncthreads();
    const int K = Ksh;

    // ---- stage contested vs rows (cols 0..99; only those affect anything) ----
    for (int idx = tid; idx < K * Q; idx += 256) {
        int k = idx / Q, i = idx - k * Q;
        vsrow[k * 101 + i] = out_vs[(size_t)b * Q * NV + clist_s[k] * NV + i];
    }
    __syncthreads();

    // ---- serial greedy over 100 class-steps (steps >= 100 are OOB no-ops) ----
    if (tid == 0) {
        for (int i = 0; i < Q; ++i) {
            // current col-i values: vs[c][i] was decremented at class-step c
            // iff query i was suppressed at step c (killset_s[c] bit i; steps
            // >= i are still zero, so ordering c<i is automatic).
            for (int k = 0; k < K; ++k) {
                int c = clist_s[k];
                float v = vsrow[k * 101 + i];
                if ((killset_s[2 * c + (i >> 6)] >> (i & 63)) & 1ull)
                    v = __fsub_rn(v, 1.0f);
                col_s[k] = v;
            }
            unsigned long long alive0 = ~0ull, alive1 = (1ull << 36) - 1;
            unsigned long long supp0 = 0ull, supp1 = 0ull;
            // stable descending selection == argsort(-col), ties -> lower index
            for (int t = 0; t < K; ++t) {
                float best = col_s[0]; int bk = 0;
                for (int k = 1; k < K; ++k) { float ck = col_s[k]; if (ck > best) { best = ck; bk = k; } }
                col_s[bk] = -3.0e38f;
                int q = clist_s[bk];
                bool al = (q < 64) ? ((alive0 >> q) & 1ull) : ((alive1 >> (q - 64)) & 1ull);
                if (al) {
                    unsigned long long m0 = mask_s[2 * q], m1 = mask_s[2 * q + 1];
                    supp0 |= alive0 & m0;
                    supp1 |= alive1 & m1;
                    alive0 &= ~m0;
                    alive1 &= ~m1;
                    if (q < 64) alive0 &= ~(1ull << q); else alive1 &= ~(1ull << (q - 64));
                }
            }
            killset_s[2 * i]     = supp0;
            killset_s[2 * i + 1] = supp1;
        }
    }
    __syncthreads();

    // ---- apply suppression deltas: vs[i][v] -= 1 iff query v killed at step i
    for (int idx = tid; idx < Q * Q; idx += 256) {
        int qrow = idx / Q, v = idx - qrow * Q;
        if ((killset_s[2 * qrow + (v >> 6)] >> (v & 63)) & 1ull) {
            size_t a = (size_t)b * Q * NV + qrow * NV + v;
            out_vs[a] = __fsub_rn(out_vs[a], 1.0f);
        }
    }
}

extern "C" void kernel_launch(void* const* d_in, const int* in_sizes, int n_in,
                              void* d_out, int out_size, void* d_ws, size_t ws_size,
                              hipStream_t stream) {
    const float* obj_logits   = (const float*)d_in[0];
    const float* verb_logits  = (const float*)d_in[1];
    const float* sub_boxes    = (const float*)d_in[2];
    const float* obj_boxes    = (const float*)d_in[3];
    const int*   target_sizes = (const int*)d_in[4];
    const int B  = in_sizes[0] / (Q * NC);   // 1024
    const int BQ = B * Q;

    float* out_vs     = (float*)d_out;                        // B*Q*117
    float* out_scores = out_vs + (size_t)B * Q * NV;          // B*Q
    float* out_labels = out_scores + (size_t)BQ;              // B*2Q
    float* out_boxes  = out_labels + (size_t)B * 2 * Q;       // B*2Q*4

    // K1: one wave per query
    k_scores<<<dim3((BQ + 3) / 4), dim3(256), 0, stream>>>(
        obj_logits, out_scores, out_labels, BQ);

    // K2: flat float4 over B*Q*117 (divisible by 4)
    const int n4 = BQ * NV / 4;
    k_vs<<<dim3((n4 + 255) / 256), dim3(256), 0, stream>>>(
        (const float4*)verb_logits, out_scores, (float4*)out_vs, n4);

    // K3: boxes + PNMS fixup, one block per batch
    k_pnms<<<dim3(B), dim3(256), 0, stream>>>(
        sub_boxes, obj_boxes, target_sizes, out_labels, out_vs, out_boxes);
}

// Round 3
// 134.943 us; speedup vs baseline: 1.7610x; 1.3377x over previous
//
#include <hip/hip_runtime.h>
#include <math.h>

#define Q 100
#define NC 81
#define NV 117
#define MAXK 48   // staged contested rows cap (global fallback beyond; ~impossible)

// ---------------------------------------------------------------------------
// K1: softmax score + argmax label. FOUR QUERIES PER WAVE (16 lanes each).
// Lane sl (0..15) of a row16 holds classes sl+16c, c=0..4 -> exactly classes
// 0..79; class 80 loaded separately (needed for softmax max/sum only).
// Width-16 butterflies: 12 ds ops per wave = 3 per query (was 24/query).
// ---------------------------------------------------------------------------
__global__ __launch_bounds__(256) void k_scores(
    const float* __restrict__ obj_logits,   // (B*Q, 81)
    float* __restrict__ out_scores,         // (B*Q)
    float* __restrict__ out_labels,         // (B, 2Q) as float
    int BQ)
{
    const int lane = threadIdx.x & 63;
    const int sl   = lane & 15;
    const int q    = blockIdx.x * 16 + (threadIdx.x >> 6) * 4 + (lane >> 4);
    if (q >= BQ) return;
    const float* lp = obj_logits + (size_t)q * NC;

    float v[5];
    #pragma unroll
    for (int c = 0; c < 5; ++c) v[c] = lp[sl + c * 16];
    const float l80 = lp[80];                 // same addr across row16: broadcast

    // local argmax over classes 0..79 (first-max-wins: ascending index scan, >)
    float bv = v[0]; int bi = sl;
    #pragma unroll
    for (int c = 1; c < 5; ++c)
        if (v[c] > bv) { bv = v[c]; bi = sl + c * 16; }
    #pragma unroll
    for (int d = 1; d < 16; d <<= 1) {
        float ov = __shfl_xor(bv, d, 16);
        int   oi = __shfl_xor(bi, d, 16);
        if (ov > bv || (ov == bv && oi < bi)) { bv = ov; bi = oi; }
    }
    const float m = fmaxf(bv, l80);           // stabilizer over all 81

    float s = (sl == 0) ? expf(l80 - m) : 0.f;
    #pragma unroll
    for (int c = 0; c < 5; ++c) s += expf(v[c] - m);
    #pragma unroll
    for (int d = 1; d < 16; d <<= 1) s += __shfl_xor(s, d, 16);

    if (sl == 0) {
        float sc = __fdiv_rn(expf(bv - m), s);
        int b = q / Q, qq = q - b * Q;
        out_scores[q] = sc;
        out_labels[(size_t)b * 2 * Q + qq]     = 0.0f;   // SUBJECT_CATEGORY_ID
        out_labels[(size_t)b * 2 * Q + Q + qq] = (float)bi;
    }
}

// ---------------------------------------------------------------------------
// K2: vs = sigmoid(verb_logits) * obj_score. Flat float4 streaming.
// scores[] (400 KB) is L2-resident broadcast. Memory-roofline kernel.
// ---------------------------------------------------------------------------
__global__ __launch_bounds__(256) void k_vs(
    const float4* __restrict__ verb4,
    const float*  __restrict__ scores,
    float4* __restrict__ out4,
    int n4)
{
    const int i = blockIdx.x * 256 + threadIdx.x;
    if (i >= n4) return;
    float4 x = verb4[i];
    const int e = i * 4;
    float xv[4] = {x.x, x.y, x.z, x.w};
    float r[4];
    #pragma unroll
    for (int j = 0; j < 4; ++j) {
        int q = (e + j) / NV;                 // magic-mul
        float sg = __fdiv_rn(1.0f, __fadd_rn(1.0f, expf(-xv[j])));
        r[j] = __fmul_rn(sg, scores[q]);
    }
    out4[i] = make_float4(r[0], r[1], r[2], r[3]);
}

// ---------------------------------------------------------------------------
// K3: boxes (xyxy*scale) + pair-NMS fixup. One block per batch (1024 blocks).
// Label bucketing: per-label 100-bit query sets; each query tests only its
// ~1.25 same-label candidates (was 99) -> mask phase ~50x fewer LDS reads.
// Fast path (no conflicting pair anywhere): write boxes and exit.
// ---------------------------------------------------------------------------
__global__ __launch_bounds__(256) void k_pnms(
    const float* __restrict__ sub_boxes,    // (B,Q,4) cxcywh
    const float* __restrict__ obj_boxes,    // (B,Q,4)
    const int*   __restrict__ target_sizes, // (B,2) h,w
    const float* __restrict__ out_labels,   // (B,2Q) float (obj labels at +Q)
    float* __restrict__ out_vs,             // (B,Q,117) written by K2
    float* __restrict__ out_boxes)          // (B,2Q,4)
{
    __shared__ float4 sb4[Q], ob4[Q];
    __shared__ float  area_s[Q], area_o[Q];
    __shared__ int    labi[Q];
    __shared__ unsigned long long lbl_bits[NC - 1][2];  // per-label query bitset
    __shared__ unsigned long long mask_s[2 * Q];        // conflict mask per query
    __shared__ unsigned long long killset_s[2 * Q];     // per step i: killed-at-i
    __shared__ int   clist_s[Q];
    __shared__ float col_s[Q];
    __shared__ float vsrow[MAXK * 101];
    __shared__ int   anyconf, Ksh;

    const int b   = blockIdx.x;
    const int tid = threadIdx.x;

    if (tid == 0) anyconf = 0;
    if (tid < 2 * Q) killset_s[tid] = 0ull;
    if (tid < 2 * (NC - 1)) ((unsigned long long*)lbl_bits)[tid] = 0ull;

    // ---- boxes (bit-exact: __f*_rn blocks FMA contraction, matches np) ----
    if (tid < 2 * Q) {
        const int q = (tid < Q) ? tid : tid - Q;
        const float fh = (float)target_sizes[2 * b];
        const float fw = (float)target_sizes[2 * b + 1];
        const float4* src = reinterpret_cast<const float4*>(tid < Q ? sub_boxes : obj_boxes);
        float4 cxy = src[(size_t)b * Q + q];
        float hw = __fmul_rn(0.5f, cxy.z);
        float hh = __fmul_rn(0.5f, cxy.w);
        float4 box;
        box.x = __fmul_rn(__fsub_rn(cxy.x, hw), fw);
        box.y = __fmul_rn(__fsub_rn(cxy.y, hh), fh);
        box.z = __fmul_rn(__fadd_rn(cxy.x, hw), fw);
        box.w = __fmul_rn(__fadd_rn(cxy.y, hh), fh);
        float area = __fmul_rn(__fsub_rn(box.z, box.x), __fsub_rn(box.w, box.y));
        if (tid < Q) {
            sb4[q] = box; area_s[q] = area;
            reinterpret_cast<float4*>(out_boxes)[(size_t)b * 2 * Q + q] = box;
            labi[q] = (int)out_labels[(size_t)b * 2 * Q + Q + q];
        } else {
            ob4[q] = box; area_o[q] = area;
            reinterpret_cast<float4*>(out_boxes)[(size_t)b * 2 * Q + Q + q] = box;
        }
    }
    __syncthreads();

    // ---- label buckets ----
    if (tid < Q)
        atomicOr(&lbl_bits[labi[tid]][tid >> 6], 1ull << (tid & 63));
    __syncthreads();

    // ---- conflict masks: only same-label candidates ----
    if (tid < Q) {
        const int j = tid;
        const float4 sj = sb4[j]; const float asj = area_s[j];
        const float4 oj = ob4[j]; const float aoj = area_o[j];
        const int lj = labi[j];
        unsigned long long bits[2] = {0ull, 0ull};
        #pragma unroll
        for (int w = 0; w < 2; ++w) {
            unsigned long long mm = lbl_bits[lj][w];
            if (w == (j >> 6)) mm &= ~(1ull << (j & 63));   // exclude self
            while (mm) {
                int kb = __builtin_ctzll(mm); mm &= mm - 1;
                int k = kb + w * 64;
                float4 sk = sb4[k];
                float wx = fmaxf(__fsub_rn(fminf(sj.z, sk.z), fmaxf(sj.x, sk.x)), 0.f);
                float wy = fmaxf(__fsub_rn(fminf(sj.w, sk.w), fmaxf(sj.y, sk.y)), 0.f);
                float inter = __fmul_rn(wx, wy);
                float uni = __fsub_rn(__fadd_rn(asj, area_s[k]), inter);
                float ious = __fdiv_rn(inter, uni);
                float4 ok = ob4[k];
                wx = fmaxf(__fsub_rn(fminf(oj.z, ok.z), fmaxf(oj.x, ok.x)), 0.f);
                wy = fmaxf(__fsub_rn(fminf(oj.w, ok.w), fmaxf(oj.y, ok.y)), 0.f);
                inter = __fmul_rn(wx, wy);
                uni = __fsub_rn(__fadd_rn(aoj, area_o[k]), inter);
                float iouo = __fdiv_rn(inter, uni);
                if (ious != ious || iouo != iouo) continue;  // np.minimum NaN -> false
                if (fminf(ious, iouo) > 0.7f) bits[w] |= 1ull << kb;
            }
        }
        mask_s[2 * j]     = bits[0];
        mask_s[2 * j + 1] = bits[1];
        if (bits[0] | bits[1]) anyconf = 1;   // benign race, same value
    }
    __syncthreads();

    if (!anyconf) return;            // fast path: boxes written, vs untouched

    // ---- contested list ----
    if (tid == 0) {
        int K = 0;
        for (int q = 0; q < Q; ++q)
            if (mask_s[2 * q] | mask_s[2 * q + 1]) clist_s[K++] = q;
        Ksh = K;
    }
    __syncthreads();
    const int K = Ksh;
    const bool staged = (K <= MAXK);

    // ---- stage contested vs rows (cols 0..99 only matter) ----
    if (staged) {
        for (int idx = tid; idx < K * Q; idx += 256) {
            int k = idx / Q, i = idx - k * Q;
            vsrow[k * 101 + i] = out_vs[(size_t)b * Q * NV + clist_s[k] * NV + i];
        }
    }
    __syncthreads();

    // ---- serial greedy over 100 class-steps (steps >= 100 are OOB no-ops) ----
    if (tid == 0) {
        for (int i = 0; i < Q; ++i) {
            // vs[c][i] was decremented at class-step c iff query i suppressed
            // at step c (killset_s[c] bit i; steps >= i still zero).
            for (int k = 0; k < K; ++k) {
                int c = clist_s[k];
                float v = staged ? vsrow[k * 101 + i]
                                 : out_vs[(size_t)b * Q * NV + c * NV + i];
                if ((killset_s[2 * c + (i >> 6)] >> (i & 63)) & 1ull)
                    v = __fsub_rn(v, 1.0f);
                col_s[k] = v;
            }
            unsigned long long alive0 = ~0ull, alive1 = (1ull << 36) - 1;
            unsigned long long supp0 = 0ull, supp1 = 0ull;
            // stable descending selection == argsort(-col), ties -> lower index
            for (int t = 0; t < K; ++t) {
                float best = col_s[0]; int bk = 0;
                for (int k = 1; k < K; ++k) { float ck = col_s[k]; if (ck > best) { best = ck; bk = k; } }
                col_s[bk] = -3.0e38f;
                int q = clist_s[bk];
                bool al = (q < 64) ? ((alive0 >> q) & 1ull) : ((alive1 >> (q - 64)) & 1ull);
                if (al) {
                    unsigned long long m0 = mask_s[2 * q], m1 = mask_s[2 * q + 1];
                    supp0 |= alive0 & m0;
                    supp1 |= alive1 & m1;
                    alive0 &= ~m0;
                    alive1 &= ~m1;
                    if (q < 64) alive0 &= ~(1ull << q); else alive1 &= ~(1ull << (q - 64));
                }
            }
            killset_s[2 * i]     = supp0;
            killset_s[2 * i + 1] = supp1;
        }
    }
    __syncthreads();

    // ---- apply deltas: vs[i][v] -= 1 iff query v killed at step i ----
    for (int idx = tid; idx < Q * Q; idx += 256) {
        int qrow = idx / Q, v = idx - qrow * Q;
        if ((killset_s[2 * qrow + (v >> 6)] >> (v & 63)) & 1ull) {
            size_t a = (size_t)b * Q * NV + qrow * NV + v;
            out_vs[a] = __fsub_rn(out_vs[a], 1.0f);
        }
    }
}

extern "C" void kernel_launch(void* const* d_in, const int* in_sizes, int n_in,
                              void* d_out, int out_size, void* d_ws, size_t ws_size,
                              hipStream_t stream) {
    const float* obj_logits   = (const float*)d_in[0];
    const float* verb_logits  = (const float*)d_in[1];
    const float* sub_boxes    = (const float*)d_in[2];
    const float* obj_boxes    = (const float*)d_in[3];
    const int*   target_sizes = (const int*)d_in[4];
    const int B  = in_sizes[0] / (Q * NC);   // 1024
    const int BQ = B * Q;

    float* out_vs     = (float*)d_out;                        // B*Q*117
    float* out_scores = out_vs + (size_t)B * Q * NV;          // B*Q
    float* out_labels = out_scores + (size_t)BQ;              // B*2Q
    float* out_boxes  = out_labels + (size_t)B * 2 * Q;       // B*2Q*4

    // K1: 4 queries per wave, 16 per block
    k_scores<<<dim3((BQ + 15) / 16), dim3(256), 0, stream>>>(
        obj_logits, out_scores, out_labels, BQ);

    // K2: flat float4 over B*Q*117 (divisible by 4)
    const int n4 = BQ * NV / 4;
    k_vs<<<dim3((n4 + 255) / 256), dim3(256), 0, stream>>>(
        (const float4*)verb_logits, out_scores, (float4*)out_vs, n4);

    // K3: boxes + PNMS fixup, one block per batch
    k_pnms<<<dim3(B), dim3(256), 0, stream>>>(
        sub_boxes, obj_boxes, target_sizes, out_labels, out_vs, out_boxes);
}

// Round 4
// 133.417 us; speedup vs baseline: 1.7812x; 1.0114x over previous
//
#include <hip/hip_runtime.h>
#include <math.h>

#define Q 100
#define NC 81
#define NV 117
#define MAXK 48   // staged contested rows cap (global fallback beyond; ~impossible)

// ---------------------------------------------------------------------------
// K12: fused softmax/argmax + vs = sigmoid(verb)*score.
// FOUR QUERIES PER WAVE (16 lanes each). Lane sl (0..15) holds classes
// sl+16c, c=0..4 -> exactly classes 0..79; class 80 broadcast-loaded (softmax
// stabilizer/sum only). Width-16 butterflies: 3 ds ops per query.
// Then the SAME wave streams its 4 queries' verb logits: 4*117 = 468
// consecutive floats = 117 float4s, base 4w*117*4B = w*1872B (16B aligned).
// Scores picked from the wave's 4 results via 4 shuffles -> no global
// scores round-trip, no second kernel launch.
// ---------------------------------------------------------------------------
__global__ __launch_bounds__(256) void k_scores_vs(
    const float*  __restrict__ obj_logits,   // (B*Q, 81)
    const float4* __restrict__ verb4,        // (B*Q*117/4)
    float* __restrict__ out_vs,              // (B,Q,117)
    float* __restrict__ out_scores,          // (B*Q)
    float* __restrict__ out_labels,          // (B, 2Q) as float
    int BQ)
{
    const int lane = threadIdx.x & 63;
    const int sl   = lane & 15;
    const int w    = blockIdx.x * 4 + (threadIdx.x >> 6);  // global wave id
    const int q    = w * 4 + (lane >> 4);                  // this row16's query
    if (q >= BQ) return;
    const float* lp = obj_logits + (size_t)q * NC;

    float v[5];
    #pragma unroll
    for (int c = 0; c < 5; ++c) v[c] = lp[sl + c * 16];
    const float l80 = lp[80];                 // same addr across row16: broadcast

    // local argmax over classes 0..79 (first-max-wins: ascending scan, strict >)
    float bv = v[0]; int bi = sl;
    #pragma unroll
    for (int c = 1; c < 5; ++c)
        if (v[c] > bv) { bv = v[c]; bi = sl + c * 16; }
    #pragma unroll
    for (int d = 1; d < 16; d <<= 1) {
        float ov = __shfl_xor(bv, d, 16);
        int   oi = __shfl_xor(bi, d, 16);
        if (ov > bv || (ov == bv && oi < bi)) { bv = ov; bi = oi; }
    }
    const float m = fmaxf(bv, l80);           // stabilizer over all 81

    float s = (sl == 0) ? expf(l80 - m) : 0.f;
    #pragma unroll
    for (int c = 0; c < 5; ++c) s += expf(v[c] - m);
    #pragma unroll
    for (int d = 1; d < 16; d <<= 1) s += __shfl_xor(s, d, 16);

    const float sc = __fdiv_rn(expf(bv - m), s);   // valid at sl==0
    if (sl == 0) {
        int b = q / Q, qq = q - b * Q;
        out_scores[q] = sc;
        out_labels[(size_t)b * 2 * Q + qq]     = 0.0f;   // SUBJECT_CATEGORY_ID
        out_labels[(size_t)b * 2 * Q + Q + qq] = (float)bi;
    }

    // broadcast the wave's 4 scores
    const float s0 = __shfl(sc, 0);
    const float s1 = __shfl(sc, 16);
    const float s2 = __shfl(sc, 32);
    const float s3 = __shfl(sc, 48);

    // stream verb logits for queries [4w, 4w+4): 117 float4s at base w*117
    const size_t base4 = (size_t)w * NV;
    float4* ovs4 = reinterpret_cast<float4*>(out_vs);
    #pragma unroll
    for (int it = 0; it < 2; ++it) {
        const int idx = it * 64 + lane;
        if (idx < NV) {
            float4 x = verb4[base4 + idx];
            float xv[4] = {x.x, x.y, x.z, x.w};
            float r[4];
            #pragma unroll
            for (int j = 0; j < 4; ++j) {
                const int e = idx * 4 + j;              // 0..467 within wave block
                const float scq = (e < NV) ? s0 : (e < 2 * NV) ? s1
                                 : (e < 3 * NV) ? s2 : s3;
                float sg = __fdiv_rn(1.0f, __fadd_rn(1.0f, expf(-xv[j])));
                r[j] = __fmul_rn(sg, scq);
            }
            ovs4[base4 + idx] = make_float4(r[0], r[1], r[2], r[3]);
        }
    }
}

// ---------------------------------------------------------------------------
// K3: boxes (xyxy*scale) + pair-NMS fixup. One block per batch (1024 blocks).
// Label bucketing: per-label 100-bit query sets; each query tests only its
// ~1.25 same-label candidates. Fast path (no conflicting pair): exit after
// writing boxes. Slow path: thread-0 serial greedy with reference semantics
// (row-i scatter quirk, OOB-drop for class-steps >= 100), parallel RMW.
// ---------------------------------------------------------------------------
__global__ __launch_bounds__(256) void k_pnms(
    const float* __restrict__ sub_boxes,    // (B,Q,4) cxcywh
    const float* __restrict__ obj_boxes,    // (B,Q,4)
    const int*   __restrict__ target_sizes, // (B,2) h,w
    const float* __restrict__ out_labels,   // (B,2Q) float (obj labels at +Q)
    float* __restrict__ out_vs,             // (B,Q,117) written by K12
    float* __restrict__ out_boxes)          // (B,2Q,4)
{
    __shared__ float4 sb4[Q], ob4[Q];
    __shared__ float  area_s[Q], area_o[Q];
    __shared__ int    labi[Q];
    __shared__ unsigned long long lbl_bits[NC - 1][2];  // per-label query bitset
    __shared__ unsigned long long mask_s[2 * Q];        // conflict mask per query
    __shared__ unsigned long long killset_s[2 * Q];     // per step i: killed-at-i
    __shared__ int   clist_s[Q];
    __shared__ float col_s[Q];
    __shared__ float vsrow[MAXK * 101];
    __shared__ int   anyconf, Ksh;

    const int b   = blockIdx.x;
    const int tid = threadIdx.x;

    if (tid == 0) anyconf = 0;
    if (tid < 2 * Q) killset_s[tid] = 0ull;
    if (tid < 2 * (NC - 1)) ((unsigned long long*)lbl_bits)[tid] = 0ull;

    // ---- boxes (bit-exact: __f*_rn blocks FMA contraction, matches np) ----
    if (tid < 2 * Q) {
        const int q = (tid < Q) ? tid : tid - Q;
        const float fh = (float)target_sizes[2 * b];
        const float fw = (float)target_sizes[2 * b + 1];
        const float4* src = reinterpret_cast<const float4*>(tid < Q ? sub_boxes : obj_boxes);
        float4 cxy = src[(size_t)b * Q + q];
        float hw = __fmul_rn(0.5f, cxy.z);
        float hh = __fmul_rn(0.5f, cxy.w);
        float4 box;
        box.x = __fmul_rn(__fsub_rn(cxy.x, hw), fw);
        box.y = __fmul_rn(__fsub_rn(cxy.y, hh), fh);
        box.z = __fmul_rn(__fadd_rn(cxy.x, hw), fw);
        box.w = __fmul_rn(__fadd_rn(cxy.y, hh), fh);
        float area = __fmul_rn(__fsub_rn(box.z, box.x), __fsub_rn(box.w, box.y));
        if (tid < Q) {
            sb4[q] = box; area_s[q] = area;
            reinterpret_cast<float4*>(out_boxes)[(size_t)b * 2 * Q + q] = box;
            labi[q] = (int)out_labels[(size_t)b * 2 * Q + Q + q];
        } else {
            ob4[q] = box; area_o[q] = area;
            reinterpret_cast<float4*>(out_boxes)[(size_t)b * 2 * Q + Q + q] = box;
        }
    }
    __syncthreads();

    // ---- label buckets ----
    if (tid < Q)
        atomicOr(&lbl_bits[labi[tid]][tid >> 6], 1ull << (tid & 63));
    __syncthreads();

    // ---- conflict masks: only same-label candidates ----
    if (tid < Q) {
        const int j = tid;
        const float4 sj = sb4[j]; const float asj = area_s[j];
        const float4 oj = ob4[j]; const float aoj = area_o[j];
        const int lj = labi[j];
        unsigned long long bits[2] = {0ull, 0ull};
        #pragma unroll
        for (int w = 0; w < 2; ++w) {
            unsigned long long mm = lbl_bits[lj][w];
            if (w == (j >> 6)) mm &= ~(1ull << (j & 63));   // exclude self
            while (mm) {
                int kb = __builtin_ctzll(mm); mm &= mm - 1;
                int k = kb + w * 64;
                float4 sk = sb4[k];
                float wx = fmaxf(__fsub_rn(fminf(sj.z, sk.z), fmaxf(sj.x, sk.x)), 0.f);
                float wy = fmaxf(__fsub_rn(fminf(sj.w, sk.w), fmaxf(sj.y, sk.y)), 0.f);
                float inter = __fmul_rn(wx, wy);
                float uni = __fsub_rn(__fadd_rn(asj, area_s[k]), inter);
                float ious = __fdiv_rn(inter, uni);
                float4 ok = ob4[k];
                wx = fmaxf(__fsub_rn(fminf(oj.z, ok.z), fmaxf(oj.x, ok.x)), 0.f);
                wy = fmaxf(__fsub_rn(fminf(oj.w, ok.w), fmaxf(oj.y, ok.y)), 0.f);
                inter = __fmul_rn(wx, wy);
                uni = __fsub_rn(__fadd_rn(aoj, area_o[k]), inter);
                float iouo = __fdiv_rn(inter, uni);
                if (ious != ious || iouo != iouo) continue;  // np.minimum NaN -> false
                if (fminf(ious, iouo) > 0.7f) bits[w] |= 1ull << kb;
            }
        }
        mask_s[2 * j]     = bits[0];
        mask_s[2 * j + 1] = bits[1];
        if (bits[0] | bits[1]) anyconf = 1;   // benign race, same value
    }
    __syncthreads();

    if (!anyconf) return;            // fast path: boxes written, vs untouched

    // ---- contested list ----
    if (tid == 0) {
        int K = 0;
        for (int q = 0; q < Q; ++q)
            if (mask_s[2 * q] | mask_s[2 * q + 1]) clist_s[K++] = q;
        Ksh = K;
    }
    __syncthreads();
    const int K = Ksh;
    const bool staged = (K <= MAXK);

    // ---- stage contested vs rows (cols 0..99 only matter) ----
    if (staged) {
        for (int idx = tid; idx < K * Q; idx += 256) {
            int k = idx / Q, i = idx - k * Q;
            vsrow[k * 101 + i] = out_vs[(size_t)b * Q * NV + clist_s[k] * NV + i];
        }
    }
    __syncthreads();

    // ---- serial greedy over 100 class-steps (steps >= 100 are OOB no-ops) ----
    if (tid == 0) {
        for (int i = 0; i < Q; ++i) {
            // vs[c][i] was decremented at class-step c iff query i suppressed
            // at step c (killset_s[c] bit i; steps >= i still zero).
            for (int k = 0; k < K; ++k) {
                int c = clist_s[k];
                float v = staged ? vsrow[k * 101 + i]
                                 : out_vs[(size_t)b * Q * NV + c * NV + i];
                if ((killset_s[2 * c + (i >> 6)] >> (i & 63)) & 1ull)
                    v = __fsub_rn(v, 1.0f);
                col_s[k] = v;
            }
            unsigned long long alive0 = ~0ull, alive1 = (1ull << 36) - 1;
            unsigned long long supp0 = 0ull, supp1 = 0ull;
            // stable descending selection == argsort(-col), ties -> lower index
            for (int t = 0; t < K; ++t) {
                float best = col_s[0]; int bk = 0;
                for (int k = 1; k < K; ++k) { float ck = col_s[k]; if (ck > best) { best = ck; bk = k; } }
                col_s[bk] = -3.0e38f;
                int q = clist_s[bk];
                bool al = (q < 64) ? ((alive0 >> q) & 1ull) : ((alive1 >> (q - 64)) & 1ull);
                if (al) {
                    unsigned long long m0 = mask_s[2 * q], m1 = mask_s[2 * q + 1];
                    supp0 |= alive0 & m0;
                    supp1 |= alive1 & m1;
                    alive0 &= ~m0;
                    alive1 &= ~m1;
                    if (q < 64) alive0 &= ~(1ull << q); else alive1 &= ~(1ull << (q - 64));
                }
            }
            killset_s[2 * i]     = supp0;
            killset_s[2 * i + 1] = supp1;
        }
    }
    __syncthreads();

    // ---- apply deltas: vs[i][v] -= 1 iff query v killed at step i ----
    for (int idx = tid; idx < Q * Q; idx += 256) {
        int qrow = idx / Q, v = idx - qrow * Q;
        if ((killset_s[2 * qrow + (v >> 6)] >> (v & 63)) & 1ull) {
            size_t a = (size_t)b * Q * NV + qrow * NV + v;
            out_vs[a] = __fsub_rn(out_vs[a], 1.0f);
        }
    }
}

extern "C" void kernel_launch(void* const* d_in, const int* in_sizes, int n_in,
                              void* d_out, int out_size, void* d_ws, size_t ws_size,
                              hipStream_t stream) {
    const float* obj_logits   = (const float*)d_in[0];
    const float* verb_logits  = (const float*)d_in[1];
    const float* sub_boxes    = (const float*)d_in[2];
    const float* obj_boxes    = (const float*)d_in[3];
    const int*   target_sizes = (const int*)d_in[4];
    const int B  = in_sizes[0] / (Q * NC);   // 1024
    const int BQ = B * Q;

    float* out_vs     = (float*)d_out;                        // B*Q*117
    float* out_scores = out_vs + (size_t)B * Q * NV;          // B*Q
    float* out_labels = out_scores + (size_t)BQ;              // B*2Q
    float* out_boxes  = out_labels + (size_t)B * 2 * Q;       // B*2Q*4

    // K12: fused scores + labels + vs. 16 queries per block (4 waves).
    k_scores_vs<<<dim3((BQ + 15) / 16), dim3(256), 0, stream>>>(
        obj_logits, (const float4*)verb_logits,
        out_vs, out_scores, out_labels, BQ);

    // K3: boxes + PNMS fixup, one block per batch
    k_pnms<<<dim3(B), dim3(256), 0, stream>>>(
        sub_boxes, obj_boxes, target_sizes, out_labels, out_vs, out_boxes);
}

// Round 5
// 131.427 us; speedup vs baseline: 1.8082x; 1.0151x over previous
//
#include <hip/hip_runtime.h>
#include <math.h>

#define Q 100
#define NC 81
#define NV 117
#define MAXK 48           // staged contested rows cap (fallback beyond; ~impossible)
#define NV4 2925          // Q*NV/4 float4s per batch (16B-aligned: 100*117*4B = 2925*16B)

// ---------------------------------------------------------------------------
// Monolithic: one block per batch, 512 threads (8 waves).
//  A: softmax/argmax, row16 layout (16 lanes/query, 3 shuffle-stages/query)
//  R2: boxes (bit-exact) + label buckets + verb-sigmoid streaming (float4)
//  masks (label-bucketed, ~1.25 candidates/query) -> fast-path exit
//  rare slow path: thread-0 serial greedy (reference semantics: row-i scatter
//  quirk, OOB-drop for class-steps >= 100), parallel RMW fixup.
// Numerics: argmax on raw logits (exact); IoU chain __f*_rn (bit-exact vs np,
// protects the 0.7 threshold); softmax/sigmoid use __expf/rcp (~1e-6 rel,
// only affects threshold-checked float outputs).
// ---------------------------------------------------------------------------
__global__ __launch_bounds__(512) void hoi_fused(
    const float*  __restrict__ obj_logits,   // (B,Q,81)
    const float4* __restrict__ verb4,        // (B, 2925)
    const float*  __restrict__ sub_boxes,    // (B,Q,4) cxcywh
    const float*  __restrict__ obj_boxes,    // (B,Q,4)
    const int*    __restrict__ target_sizes, // (B,2) h,w
    float* __restrict__ out_vs,              // (B,Q,117)
    float* __restrict__ out_scores,          // (B,Q)
    float* __restrict__ out_labels,          // (B,2Q)
    float* __restrict__ out_boxes)           // (B,2Q,4)
{
    __shared__ float  score_s[Q];
    __shared__ int    labi[Q];
    __shared__ float4 sb4[Q], ob4[Q];
    __shared__ float  area_s[Q], area_o[Q];
    __shared__ unsigned long long lbl_bits[NC - 1][2];  // per-label query bitset
    __shared__ unsigned long long mask_s[2 * Q];        // conflict mask per query
    __shared__ unsigned long long killset_s[2 * Q];     // per step i: killed-at-i
    __shared__ int   clist_s[Q];
    __shared__ float col_s[Q];
    __shared__ float vsrow[MAXK * 101];
    __shared__ int   anyconf, Ksh;

    const int b    = blockIdx.x;
    const int tid  = threadIdx.x;
    const int lane = tid & 63;
    const int sl   = lane & 15;
    const int r16  = tid >> 4;           // 0..31 row16 id

    // ---- init (pre-sync1) ----
    if (tid == 0) anyconf = 0;
    if (tid < 2 * Q) killset_s[tid] = 0ull;
    if (tid < 2 * (NC - 1)) ((unsigned long long*)lbl_bits)[tid] = 0ull;

    // ---- Phase A: softmax score + argmax label, row16 layout ----
    for (int qi = r16; qi < Q; qi += 32) {
        const float* lp = obj_logits + ((size_t)b * Q + qi) * NC;
        float v[5];
        #pragma unroll
        for (int c = 0; c < 5; ++c) v[c] = lp[sl + c * 16];
        const float l80 = lp[80];

        // argmax over classes 0..79 on RAW logits (exact, first-max-wins)
        float bv = v[0]; int bi = sl;
        #pragma unroll
        for (int c = 1; c < 5; ++c)
            if (v[c] > bv) { bv = v[c]; bi = sl + c * 16; }
        #pragma unroll
        for (int d = 1; d < 16; d <<= 1) {
            float ov = __shfl_xor(bv, d, 16);
            int   oi = __shfl_xor(bi, d, 16);
            if (ov > bv || (ov == bv && oi < bi)) { bv = ov; bi = oi; }
        }
        const float m = fmaxf(bv, l80);       // stabilizer over all 81

        float s = (sl == 0) ? __expf(l80 - m) : 0.f;
        #pragma unroll
        for (int c = 0; c < 5; ++c) s += __expf(v[c] - m);
        #pragma unroll
        for (int d = 1; d < 16; d <<= 1) s += __shfl_xor(s, d, 16);

        if (sl == 0) {
            score_s[qi] = __fmul_rn(__expf(bv - m), __builtin_amdgcn_rcpf(s));
            labi[qi] = bi;
        }
    }
    __syncthreads();   // sync1: score_s, labi ready

    // ---- Region 2a: boxes (bit-exact) + coalesced scores/labels writes ----
    if (tid < 2 * Q) {
        const int q = (tid < Q) ? tid : tid - Q;
        const float fh = (float)target_sizes[2 * b];
        const float fw = (float)target_sizes[2 * b + 1];
        const float4* src = reinterpret_cast<const float4*>(tid < Q ? sub_boxes : obj_boxes);
        float4 cxy = src[(size_t)b * Q + q];
        float hw = __fmul_rn(0.5f, cxy.z);
        float hh = __fmul_rn(0.5f, cxy.w);
        float4 box;
        box.x = __fmul_rn(__fsub_rn(cxy.x, hw), fw);
        box.y = __fmul_rn(__fsub_rn(cxy.y, hh), fh);
        box.z = __fmul_rn(__fadd_rn(cxy.x, hw), fw);
        box.w = __fmul_rn(__fadd_rn(cxy.y, hh), fh);
        float area = __fmul_rn(__fsub_rn(box.z, box.x), __fsub_rn(box.w, box.y));
        if (tid < Q) { sb4[q] = box; area_s[q] = area; }
        else         { ob4[q] = box; area_o[q] = area; }
        reinterpret_cast<float4*>(out_boxes)[(size_t)b * 2 * Q + tid] = box;
        out_labels[(size_t)b * 2 * Q + tid] = (tid < Q) ? 0.0f : (float)labi[q];
    }
    if (tid < Q) {
        out_scores[(size_t)b * Q + tid] = score_s[tid];
        atomicOr(&lbl_bits[labi[tid]][tid >> 6], 1ull << (tid & 63));  // buckets
    }

    // ---- Region 2b: verb sigmoid streaming (all 512 threads) ----
    {
        const size_t base4 = (size_t)b * NV4;
        float4* ovs4 = reinterpret_cast<float4*>(out_vs);
        for (int idx = tid; idx < NV4; idx += 512) {
            float4 x = verb4[base4 + idx];
            float xv[4] = {x.x, x.y, x.z, x.w};
            float r[4];
            #pragma unroll
            for (int j = 0; j < 4; ++j) {
                int lq = (idx * 4 + j) / NV;          // magic-mul, local query
                float sg = __builtin_amdgcn_rcpf(__fadd_rn(1.0f, __expf(-xv[j])));
                r[j] = __fmul_rn(sg, score_s[lq]);
            }
            ovs4[base4 + idx] = make_float4(r[0], r[1], r[2], r[3]);
        }
    }
    __syncthreads();   // sync2: sb4/ob4/areas/lbl_bits ready

    // ---- masks: only same-label candidates ----
    if (tid < Q) {
        const int j = tid;
        const float4 sj = sb4[j]; const float asj = area_s[j];
        const float4 oj = ob4[j]; const float aoj = area_o[j];
        const int lj = labi[j];
        unsigned long long bits[2] = {0ull, 0ull};
        #pragma unroll
        for (int w = 0; w < 2; ++w) {
            unsigned long long mm = lbl_bits[lj][w];
            if (w == (j >> 6)) mm &= ~(1ull << (j & 63));   // exclude self
            while (mm) {
                int kb = __builtin_ctzll(mm); mm &= mm - 1;
                int k = kb + w * 64;
                float4 sk = sb4[k];
                float wx = fmaxf(__fsub_rn(fminf(sj.z, sk.z), fmaxf(sj.x, sk.x)), 0.f);
                float wy = fmaxf(__fsub_rn(fminf(sj.w, sk.w), fmaxf(sj.y, sk.y)), 0.f);
                float inter = __fmul_rn(wx, wy);
                float uni = __fsub_rn(__fadd_rn(asj, area_s[k]), inter);
                float ious = __fdiv_rn(inter, uni);
                float4 ok = ob4[k];
                wx = fmaxf(__fsub_rn(fminf(oj.z, ok.z), fmaxf(oj.x, ok.x)), 0.f);
                wy = fmaxf(__fsub_rn(fminf(oj.w, ok.w), fmaxf(oj.y, ok.y)), 0.f);
                inter = __fmul_rn(wx, wy);
                uni = __fsub_rn(__fadd_rn(aoj, area_o[k]), inter);
                float iouo = __fdiv_rn(inter, uni);
                if (ious != ious || iouo != iouo) continue;  // np.minimum NaN -> false
                if (fminf(ious, iouo) > 0.7f) bits[w] |= 1ull << kb;
            }
        }
        mask_s[2 * j]     = bits[0];
        mask_s[2 * j + 1] = bits[1];
        if (bits[0] | bits[1]) anyconf = 1;   // benign race, same value
    }
    __syncthreads();   // sync3: masks + anyconf ready; streaming writes drained

    if (!anyconf) return;            // fast path (common case)

    // ---- slow path: contested list ----
    if (tid == 0) {
        int K = 0;
        for (int q = 0; q < Q; ++q)
            if (mask_s[2 * q] | mask_s[2 * q + 1]) clist_s[K++] = q;
        Ksh = K;
    }
    __syncthreads();
    const int K = Ksh;
    const bool staged = (K <= MAXK);

    // stage contested vs rows (cols 0..99 only matter); L2-hot re-read
    if (staged) {
        for (int idx = tid; idx < K * Q; idx += 512) {
            int k = idx / Q, i = idx - k * Q;
            vsrow[k * 101 + i] = out_vs[(size_t)b * Q * NV + clist_s[k] * NV + i];
        }
    }
    __syncthreads();

    // serial greedy over 100 class-steps (steps >= 100 are OOB no-ops)
    if (tid == 0) {
        for (int i = 0; i < Q; ++i) {
            // vs[c][i] was decremented at class-step c iff query i suppressed
            // at step c (killset_s[c] bit i; steps >= i still zero).
            for (int k = 0; k < K; ++k) {
                int c = clist_s[k];
                float v = staged ? vsrow[k * 101 + i]
                                 : out_vs[(size_t)b * Q * NV + c * NV + i];
                if ((killset_s[2 * c + (i >> 6)] >> (i & 63)) & 1ull)
                    v = __fsub_rn(v, 1.0f);
                col_s[k] = v;
            }
            unsigned long long alive0 = ~0ull, alive1 = (1ull << 36) - 1;
            unsigned long long supp0 = 0ull, supp1 = 0ull;
            // stable descending selection == argsort(-col), ties -> lower index
            for (int t = 0; t < K; ++t) {
                float best = col_s[0]; int bk = 0;
                for (int k = 1; k < K; ++k) { float ck = col_s[k]; if (ck > best) { best = ck; bk = k; } }
                col_s[bk] = -3.0e38f;
                int q = clist_s[bk];
                bool al = (q < 64) ? ((alive0 >> q) & 1ull) : ((alive1 >> (q - 64)) & 1ull);
                if (al) {
                    unsigned long long m0 = mask_s[2 * q], m1 = mask_s[2 * q + 1];
                    supp0 |= alive0 & m0;
                    supp1 |= alive1 & m1;
                    alive0 &= ~m0;
                    alive1 &= ~m1;
                    if (q < 64) alive0 &= ~(1ull << q); else alive1 &= ~(1ull << (q - 64));
                }
            }
            killset_s[2 * i]     = supp0;
            killset_s[2 * i + 1] = supp1;
        }
    }
    __syncthreads();

    // apply deltas: vs[i][v] -= 1 iff query v killed at step i
    for (int idx = tid; idx < Q * Q; idx += 512) {
        int qrow = idx / Q, v = idx - qrow * Q;
        if ((killset_s[2 * qrow + (v >> 6)] >> (v & 63)) & 1ull) {
            size_t a = (size_t)b * Q * NV + qrow * NV + v;
            out_vs[a] = __fsub_rn(out_vs[a], 1.0f);
        }
    }
}

extern "C" void kernel_launch(void* const* d_in, const int* in_sizes, int n_in,
                              void* d_out, int out_size, void* d_ws, size_t ws_size,
                              hipStream_t stream) {
    const float* obj_logits   = (const float*)d_in[0];
    const float* verb_logits  = (const float*)d_in[1];
    const float* sub_boxes    = (const float*)d_in[2];
    const float* obj_boxes    = (const float*)d_in[3];
    const int*   target_sizes = (const int*)d_in[4];
    const int B  = in_sizes[0] / (Q * NC);   // 1024

    float* out_vs     = (float*)d_out;                        // B*Q*117
    float* out_scores = out_vs + (size_t)B * Q * NV;          // B*Q
    float* out_labels = out_scores + (size_t)B * Q;           // B*2Q
    float* out_boxes  = out_labels + (size_t)B * 2 * Q;       // B*2Q*4

    hoi_fused<<<dim3(B), dim3(512), 0, stream>>>(
        obj_logits, (const float4*)verb_logits,
        sub_boxes, obj_boxes, target_sizes,
        out_vs, out_scores, out_labels, out_boxes);
}